// Round 19
// baseline (309.367 us; speedup 1.0000x reference)
//
#include <hip/hip_runtime.h>
#include <hip/hip_bf16.h>
#include <cstdint>
#include <math.h>

#define B_DIM 32
#define T_DIM 1000
#define D_DIM 768
#define V_DIM 31
#define L_DIM 200
#define S_DIM 401      // 2L+1 CTC states
#define S_PAD 512      // 2 waves x 64 lanes x 4 states
#define VSTRIDE 32     // padded prob-row stride: 32 floats = 128 B

typedef __bf16 bf16x8 __attribute__((ext_vector_type(8)));
typedef float  f32x4  __attribute__((ext_vector_type(4)));
typedef float  f32x2  __attribute__((ext_vector_type(2)));
typedef __attribute__((address_space(3))) float lds_float;

#define SB() __builtin_amdgcn_sched_barrier(0)

// Wave-wide shift-up-by-1 via DPP WAVE_SHR1 (0x138): pure VALU. Lane 0 -> 0.
__device__ __forceinline__ float shup1_f(float x) {
    int r = __builtin_amdgcn_update_dpp(0, __float_as_int(x), 0x138, 0xF, 0xF, true);
    return __int_as_float(r);
}
__device__ __forceinline__ int shup1_i(int x) {
    return __builtin_amdgcn_update_dpp(0, x, 0x138, 0xF, 0xF, true);
}

// --- asm helpers (counted waits; rule #18: sched_barrier after lgkmcnt) ----
#define WTn(n) do { asm volatile("s_waitcnt lgkmcnt(" #n ")" ::: "memory"); SB(); } while (0)
#define BARR() do { asm volatile("s_waitcnt lgkmcnt(0)" ::: "memory"); SB(); \
                    asm volatile("s_barrier" ::: "memory"); SB(); } while (0)
#define RD3(G, off) do { \
    asm volatile("ds_read_b32 %0, %1 offset:" #off : "=v"(G[0]) : "v"(va[0])); \
    asm volatile("ds_read_b32 %0, %1 offset:" #off : "=v"(G[1]) : "v"(va[1])); \
    asm volatile("ds_read_b32 %0, %1 offset:" #off : "=v"(G[2]) : "v"(va[2])); } while (0)
#define RDE(E, base, off) \
    asm volatile("ds_read_b64 %0, %1 offset:" #off : "=v"(E) : "v"(base))
#define WB(o0, o1) \
    asm volatile("ds_write2_b32 %0, %1, %2 offset0:" #o0 " offset1:" #o1 \
                 :: "v"(wcur), "v"(a[3]), "v"(z2) : "memory")

// ---------------------------------------------------------------------------
// Fused kernel, grid = 32 (one block per batch), 4 waves:
//   waves 0,1: CTC recursion (r17 2-wave skewed pipeline, verified)
//   waves 2,3: in-block head producers — logits+softmax for 16-row chunks,
//              written directly into the lbuf LDS slots (no global probs, no
//              DMA, no cross-block sync). wave2 = even chunks, wave3 = odd.
// Barrier schedule: F+2 barriers on ALL waves (E0 prologue, E1..EF loop,
// E_{F+1} post). Chunk c is produced during superstep c-1 (chunks 0,1 + row0
// in prologue), consumed by wave0 at c+1 and wave1 at c+2, slot reused at c+3.
// ---------------------------------------------------------------------------
__global__ __launch_bounds__(256, 1) void fused_kernel(
    const float* __restrict__ pred,
    const int* __restrict__ targets,
    const int* __restrict__ in_lens,
    const int* __restrict__ tgt_lens,
    const float* __restrict__ W,
    const float* __restrict__ bias,
    float* __restrict__ out_nll)
{
    __shared__ float lbuf[4][16][VSTRIDE];          // 8 KB, slot = chunk%4
    __shared__ __align__(8) float bndb[3][16][2];   // boundary ring (a255, zbits)
    __shared__ float trash[256];                    // decoy for lane!=63 writes
    __shared__ float sal[S_PAD];
    __shared__ float row0b[VSTRIDE];                // probs row 0 (for init)
    __shared__ __bf16 wlds[32][D_DIM];              // W bf16 (row 31 = zeros), 48 KB
    __shared__ float biasl[32];
    __shared__ float csta[2][16][33];               // per-producer C staging

    const int b    = blockIdx.x;
    const int tid  = threadIdx.x;
    const int lane = tid & 63;
    const int w    = __builtin_amdgcn_readfirstlane(tid >> 6);
    const int Tin  = in_lens[b];
    const int tl   = tgt_lens[b];
    const int* tgt = targets + b * L_DIM;
    const float* __restrict__ predb = pred + (size_t)b * T_DIM * D_DIM;

    const int NS = Tin - 1;        // steps t = 1..Tin-1
    const int F  = NS >> 4;        // full chunks (>= 49)
    const int R  = NS & 15;        // remainder steps

    float* lbp = &lbuf[0][0][0];

    if (w >= 2) {
        // ========================= PRODUCER WAVES =========================
        const int pidx = w - 2;
        // W -> bf16 LDS (both waves write identical values: benign race).
        for (int i = lane; i < 32 * D_DIM; i += 64) {
            const int r = i / D_DIM, k = i - r * D_DIM;
            wlds[r][k] = (r < V_DIM) ? (__bf16)W[r * D_DIM + k] : (__bf16)0.f;
        }
        if (lane < 32) biasl[lane] = (lane < V_DIM) ? bias[lane] : 0.f;

        const int cc = lane & 15;
        const int h2 = lane >> 4;
        float (*cs)[33] = csta[pidx];

        auto PRODUCE = [&](int rbase, float* dstbase, bool only0) {
            int arow = rbase + cc;
            if (arow > T_DIM - 1) arow = T_DIM - 1;
            const float* pA = predb + (size_t)arow * D_DIM + h2 * 8;
            f32x4 c0, c1;
#pragma unroll
            for (int i = 0; i < 4; ++i) { c0[i] = 0.f; c1[i] = 0.f; }
#pragma unroll
            for (int kt = 0; kt < 24; ++kt) {
                const float4 a0 = *reinterpret_cast<const float4*>(pA + kt * 32);
                const float4 a1 = *reinterpret_cast<const float4*>(pA + kt * 32 + 4);
                bf16x8 af;
                af[0] = (__bf16)a0.x; af[1] = (__bf16)a0.y;
                af[2] = (__bf16)a0.z; af[3] = (__bf16)a0.w;
                af[4] = (__bf16)a1.x; af[5] = (__bf16)a1.y;
                af[6] = (__bf16)a1.z; af[7] = (__bf16)a1.w;
                const bf16x8 b0 = *reinterpret_cast<const bf16x8*>(
                    &wlds[cc][h2 * 8 + kt * 32]);
                const bf16x8 b1 = *reinterpret_cast<const bf16x8*>(
                    &wlds[16 + cc][h2 * 8 + kt * 32]);
                c0 = __builtin_amdgcn_mfma_f32_16x16x32_bf16(af, b0, c0, 0, 0, 0);
                c1 = __builtin_amdgcn_mfma_f32_16x16x32_bf16(af, b1, c1, 0, 0, 0);
            }
            // C layout (m89): col = lane&15, row = (lane>>4)*4 + reg
#pragma unroll
            for (int r = 0; r < 4; ++r) {
                cs[h2 * 4 + r][cc]      = c0[r];
                cs[h2 * 4 + r][16 + cc] = c1[r];
            }
            asm volatile("s_waitcnt lgkmcnt(0)" ::: "memory");
            SB();
            if (lane < 16 && (!only0 || lane == 0)) {
                float lg[V_DIM];
                float m = -1e30f;
#pragma unroll
                for (int v = 0; v < V_DIM; ++v) {
                    lg[v] = cs[lane][v] + biasl[v];
                    m = fmaxf(m, lg[v]);
                }
                float e[32];
                float s = 0.f;
#pragma unroll
                for (int v = 0; v < V_DIM; ++v) { e[v] = __expf(lg[v] - m); s += e[v]; }
                const float inv = 1.0f / s;
#pragma unroll
                for (int v = 0; v < V_DIM; ++v) e[v] *= inv;
                e[31] = 0.f;
                float* dst = dstbase + lane * VSTRIDE;
#pragma unroll
                for (int q = 0; q < 8; ++q)
                    *reinterpret_cast<float4*>(dst + q * 4) =
                        *reinterpret_cast<float4*>(&e[q * 4]);
            }
        };

        // prologue: row0 + chunks 0,1
        if (pidx == 0) {
            PRODUCE(0, row0b, true);            // rows 0..15, keep row 0
            PRODUCE(1, lbp + 0 * 512, false);   // chunk 0 -> slot 0
        } else {
            PRODUCE(17, lbp + 1 * 512, false);  // chunk 1 -> slot 1
        }
        BARR();                                  // E0
        for (int k = 1; k <= F + 1; ++k) {
            const int c = k + 1;
            if (c <= F && (c & 1) == pidx)
                PRODUCE(16 * c + 1, lbp + (c & 3) * 512, false);
            BARR();                              // E_k
        }
        return;
    }

    // ============================== CTC ==============================
    // per-lane labels (2 odd states) + skip masks; pad states inert
    int k0 = (w ? 128 : 0) + 2 * lane;
    int k1 = k0 + 1;
    if (k0 > L_DIM - 1) k0 = L_DIM - 1;
    if (k1 > L_DIM - 1) k1 = L_DIM - 1;
    const int loff0 = tgt[k0];
    const int loff1 = tgt[k1];
    const int k0m   = (k0 > 0) ? k0 - 1 : 0;
    const float m20 = (w == 0 && lane == 0) ? 0.f : ((loff0 != tgt[k0m]) ? 1.f : 0.f);
    const float m21 = (loff1 != tgt[k1 - 1]) ? 1.f : 0.f;

    const uint32_t lb_base  = (uint32_t)(uintptr_t)(lds_float*)&lbuf[0][0][0];
    const uint32_t bnd_base = (uint32_t)(uintptr_t)(lds_float*)&bndb[0][0][0];
    const uint32_t tr_base  = (uint32_t)(uintptr_t)(lds_float*)&trash[0];

    float a[4] = {0.f, 0.f, 0.f, 0.f};
    int   z2 = 0;
    const float fz = (lane == 0) ? 0.f : 1.0f;
    float f = fz;

    uint32_t va[3];
    va[0] = lb_base + (uint32_t)(loff0 * 4);
    va[1] = lb_base + (uint32_t)(loff1 * 4);
    va[2] = lb_base;

    float GA[3], GB[3], GC[3], GD[3];

    if (w == 0) {
        // ============================ WAVE 0 ============================
        BARR();                           // E0: chunks 0,1 + row0b ready
        if (lane == 0) {                  // t=0 init from LDS row 0
            a[0] = row0b[0];
            a[1] = row0b[loff0];
        }
        const uint32_t wsel = (lane == 63) ? bnd_base : (tr_base + (uint32_t)(lane * 4));
        uint32_t wcur = wsel;
        {   // initial boundary entry (chunk -1, entry 15) = slot2,e15: zeros
            const uint32_t winit = wsel + 256;
            asm volatile("ds_write2_b32 %0, %1, %2 offset0:30 offset1:31"
                         :: "v"(winit), "v"(a[3]), "v"(z2) : "memory");
        }

        auto ST0 = [&](const float (&G)[3]) {
            const float s3p = shup1_f(a[3]);
            const float am1 = s3p * f;
            const float n0 = (a[0] + am1) * G[2];
            const float n1 = (a[1] + a[0] + m20 * am1) * G[0];
            const float n2 = (a[2] + a[1]) * G[2];
            const float n3 = (a[3] + a[2] + m21 * a[1]) * G[1];
            a[0] = n0; a[1] = n1; a[2] = n2; a[3] = n3;
        };
        auto REN0 = [&]() {
            const float mx = fmaxf(fmaxf(a[0], a[1]), fmaxf(a[2], a[3]));
            int e; (void)frexpf(mx, &e);
            const int zc = z2 + e;
            const int zp = shup1_i(zc);
            z2 = (mx > 0.f) ? zc : zp;
            a[0] = ldexpf(a[0], -e); a[1] = ldexpf(a[1], -e);
            a[2] = ldexpf(a[2], -e); a[3] = ldexpf(a[3], -e);
            const int dz = zp - z2;
            f = ldexpf(fz, dz);
        };

        uint32_t ro = 0;
        RD3(GA, 0);                       // chunk 0 rows 0,1
        RD3(GB, 128);

        for (int s = 0; s < F; ++s) {
            RD3(GC, 256);  WTn(8); ST0(GA);         WB(0, 1);
            RD3(GD, 384);  WTn(8); ST0(GB); REN0(); WB(2, 3);
            RD3(GA, 512);  WTn(8); ST0(GC);         WB(4, 5);
            RD3(GB, 640);  WTn(8); ST0(GD); REN0(); WB(6, 7);
            RD3(GC, 768);  WTn(8); ST0(GA);         WB(8, 9);
            RD3(GD, 896);  WTn(8); ST0(GB); REN0(); WB(10, 11);
            RD3(GA, 1024); WTn(8); ST0(GC);         WB(12, 13);
            RD3(GB, 1152); WTn(8); ST0(GD); REN0(); WB(14, 15);
            RD3(GC, 1280); WTn(8); ST0(GA);         WB(16, 17);
            RD3(GD, 1408); WTn(8); ST0(GB); REN0(); WB(18, 19);
            RD3(GA, 1536); WTn(8); ST0(GC);         WB(20, 21);
            RD3(GB, 1664); WTn(8); ST0(GD); REN0(); WB(22, 23);
            RD3(GC, 1792); WTn(8); ST0(GA);         WB(24, 25);
            RD3(GD, 1920); WTn(8); ST0(GB); REN0(); WB(26, 27);
            // advance gather ring to next slot (chunk s+1, produced at s-1)
            ro = (ro + 2048u) & 8191u;
            va[0] = lb_base + ro + (uint32_t)(loff0 * 4);
            va[1] = lb_base + ro + (uint32_t)(loff1 * 4);
            va[2] = lb_base + ro;
            RD3(GA, 0);    WTn(8); ST0(GC);         WB(28, 29);
            RD3(GB, 128);  WTn(8); ST0(GD); REN0(); WB(30, 31);
            wcur = (wcur == wsel + 256u) ? wsel : wcur + 128u;
            BARR();                              // E_{s+1}
        }
        // partial superstep F: R steps (GA,GB preloaded rows 0,1 of slot F)
        if (R > 0)  { RD3(GC, 256);  WTn(8); ST0(GA);         WB(0, 1); }
        if (R > 1)  { RD3(GD, 384);  WTn(8); ST0(GB); REN0(); WB(2, 3); }
        if (R > 2)  { RD3(GA, 512);  WTn(8); ST0(GC);         WB(4, 5); }
        if (R > 3)  { RD3(GB, 640);  WTn(8); ST0(GD); REN0(); WB(6, 7); }
        if (R > 4)  { RD3(GC, 768);  WTn(8); ST0(GA);         WB(8, 9); }
        if (R > 5)  { RD3(GD, 896);  WTn(8); ST0(GB); REN0(); WB(10, 11); }
        if (R > 6)  { RD3(GA, 1024); WTn(8); ST0(GC);         WB(12, 13); }
        if (R > 7)  { RD3(GB, 1152); WTn(8); ST0(GD); REN0(); WB(14, 15); }
        if (R > 8)  { RD3(GC, 1280); WTn(8); ST0(GA);         WB(16, 17); }
        if (R > 9)  { RD3(GD, 1408); WTn(8); ST0(GB); REN0(); WB(18, 19); }
        if (R > 10) { RD3(GA, 1536); WTn(8); ST0(GC);         WB(20, 21); }
        if (R > 11) { RD3(GB, 1664); WTn(8); ST0(GD); REN0(); WB(22, 23); }
        if (R > 12) { RD3(GC, 1792); WTn(8); ST0(GA);         WB(24, 25); }
        if (R > 13) { RD3(GD, 1920); WTn(8); ST0(GB); REN0(); WB(26, 27); }
        if (R > 14) { WTn(4); ST0(GC); WB(28, 29); }
        BARR();                                  // E_{F+1}
        return;
    } else {
        // ============================ WAVE 1 ============================
        const float fbz = (lane == 0) ? 1.0f : 0.f;
        f32x2 EA, EB, EC, ED;

        auto ST1 = [&](const float (&G)[3], const f32x2& E) {
            const float s3p = shup1_f(a[3]);
            float am1 = s3p * f;
            const int dzb = __float_as_int(E[1]) - z2;
            am1 = fmaf(E[0], ldexpf(fbz, dzb), am1);
            const float n0 = (a[0] + am1) * G[2];
            const float n1 = (a[1] + a[0] + m20 * am1) * G[0];
            const float n2 = (a[2] + a[1]) * G[2];
            const float n3 = (a[3] + a[2] + m21 * a[1]) * G[1];
            a[0] = n0; a[1] = n1; a[2] = n2; a[3] = n3;
        };
        auto REN1 = [&](const f32x2& E) {
            const float mx = fmaxf(fmaxf(a[0], a[1]), fmaxf(a[2], a[3]));
            int e; (void)frexpf(mx, &e);
            const int zc = z2 + e;
            int zp = shup1_i(zc);
            zp = (lane == 0) ? __float_as_int(E[1]) : zp;   // adopt across waves
            z2 = (mx > 0.f) ? zc : zp;
            a[0] = ldexpf(a[0], -e); a[1] = ldexpf(a[1], -e);
            a[2] = ldexpf(a[2], -e); a[3] = ldexpf(a[3], -e);
            const int dz = zp - z2;
            f = ldexpf(fz, dz);
        };

        uint32_t ro = 0;
        uint32_t cb = bnd_base, pb = bnd_base + 256u;
        BARR();   // E0
        BARR();   // E1 (skew idle)
        for (int c = 0; c < F; ++c) {
            RD3(GA, 0);    RDE(EA, pb, 120);
            RD3(GB, 128);  RDE(EB, cb, 0);
            WTn(0);
            RD3(GC, 256);  RDE(EC, cb, 8);   WTn(8); ST1(GA, EA);
            RD3(GD, 384);  RDE(ED, cb, 16);  WTn(8); ST1(GB, EB); REN1(EB);
            RD3(GA, 512);  RDE(EA, cb, 24);  WTn(8); ST1(GC, EC);
            RD3(GB, 640);  RDE(EB, cb, 32);  WTn(8); ST1(GD, ED); REN1(ED);
            RD3(GC, 768);  RDE(EC, cb, 40);  WTn(8); ST1(GA, EA);
            RD3(GD, 896);  RDE(ED, cb, 48);  WTn(8); ST1(GB, EB); REN1(EB);
            RD3(GA, 1024); RDE(EA, cb, 56);  WTn(8); ST1(GC, EC);
            RD3(GB, 1152); RDE(EB, cb, 64);  WTn(8); ST1(GD, ED); REN1(ED);
            RD3(GC, 1280); RDE(EC, cb, 72);  WTn(8); ST1(GA, EA);
            RD3(GD, 1408); RDE(ED, cb, 80);  WTn(8); ST1(GB, EB); REN1(EB);
            RD3(GA, 1536); RDE(EA, cb, 88);  WTn(8); ST1(GC, EC);
            RD3(GB, 1664); RDE(EB, cb, 96);  WTn(8); ST1(GD, ED); REN1(ED);
            RD3(GC, 1792); RDE(EC, cb, 104); WTn(8); ST1(GA, EA);
            RD3(GD, 1920); RDE(ED, cb, 112); WTn(8); ST1(GB, EB); REN1(EB);
            WTn(4); ST1(GC, EC);
            WTn(0); ST1(GD, ED); REN1(ED);
            ro = (ro + 2048u) & 8191u;
            va[0] = lb_base + ro + (uint32_t)(loff0 * 4);
            va[1] = lb_base + ro + (uint32_t)(loff1 * 4);
            va[2] = lb_base + ro;
            pb = cb;
            cb = (cb == bnd_base + 256u) ? bnd_base : cb + 128u;
            BARR();                              // E_{c+2}
        }
        // free-run: chunk F (R steps); all inputs stable after E_{F+1}
        if (R > 0) {
            RD3(GA, 0);   RDE(EA, pb, 120);
            RD3(GB, 128); RDE(EB, cb, 0);
            WTn(0);
            RD3(GC, 256); RDE(EC, cb, 8); WTn(8); ST1(GA, EA);
        }
        if (R > 1)  { RD3(GD, 384);  RDE(ED, cb, 16);  WTn(8); ST1(GB, EB); REN1(EB); }
        if (R > 2)  { RD3(GA, 512);  RDE(EA, cb, 24);  WTn(8); ST1(GC, EC); }
        if (R > 3)  { RD3(GB, 640);  RDE(EB, cb, 32);  WTn(8); ST1(GD, ED); REN1(ED); }
        if (R > 4)  { RD3(GC, 768);  RDE(EC, cb, 40);  WTn(8); ST1(GA, EA); }
        if (R > 5)  { RD3(GD, 896);  RDE(ED, cb, 48);  WTn(8); ST1(GB, EB); REN1(EB); }
        if (R > 6)  { RD3(GA, 1024); RDE(EA, cb, 56);  WTn(8); ST1(GC, EC); }
        if (R > 7)  { RD3(GB, 1152); RDE(EB, cb, 64);  WTn(8); ST1(GD, ED); REN1(ED); }
        if (R > 8)  { RD3(GC, 1280); RDE(EC, cb, 72);  WTn(8); ST1(GA, EA); }
        if (R > 9)  { RD3(GD, 1408); RDE(ED, cb, 80);  WTn(8); ST1(GB, EB); REN1(EB); }
        if (R > 10) { RD3(GA, 1536); RDE(EA, cb, 88);  WTn(8); ST1(GC, EC); }
        if (R > 11) { RD3(GB, 1664); RDE(EB, cb, 96);  WTn(8); ST1(GD, ED); REN1(ED); }
        if (R > 12) { RD3(GC, 1792); RDE(EC, cb, 104); WTn(8); ST1(GA, EA); }
        if (R > 13) { RD3(GD, 1920); RDE(ED, cb, 112); WTn(8); ST1(GB, EB); REN1(EB); }
        if (R > 14) { WTn(4); ST1(GC, EC); }
        WTn(0);

        // absolute log-alpha for states 256..511; final states are >= 299
        const float zln2 = (float)z2 * 0.69314718055994530942f;
        sal[256 + 4 * lane + 0] = __logf(a[0]) + zln2;
        sal[256 + 4 * lane + 1] = __logf(a[1]) + zln2;
        sal[256 + 4 * lane + 2] = __logf(a[2]) + zln2;
        sal[256 + 4 * lane + 3] = __logf(a[3]) + zln2;
        asm volatile("s_waitcnt lgkmcnt(0)" ::: "memory");
        SB();
        if (lane == 0) {
            const float x0 = sal[2 * tl - 1];
            const float x1 = sal[2 * tl];
            const float m  = fmaxf(x0, x1);
            float nll = -(m + __logf(__expf(x0 - m) + __expf(x1 - m)));
            if (!(nll < 1e29f)) nll = 0.f;       // zero_infinity (inf/NaN too)
            out_nll[b] = nll / (float)tl;
        }
    }
}

// ---------------------------------------------------------------------------
// Kernel 3: deterministic mean over B
// ---------------------------------------------------------------------------
__global__ void finalize_kernel(const float* __restrict__ nll, float* __restrict__ out)
{
    if (threadIdx.x == 0 && blockIdx.x == 0) {
        float s = 0.f;
        for (int i = 0; i < B_DIM; ++i) s += nll[i];
        out[0] = s * (1.0f / (float)B_DIM);
    }
}

extern "C" void kernel_launch(void* const* d_in, const int* in_sizes, int n_in,
                              void* d_out, int out_size, void* d_ws, size_t ws_size,
                              hipStream_t stream)
{
    const float* pred     = (const float*)d_in[0];
    const int*   targets  = (const int*)d_in[1];
    const int*   in_lens  = (const int*)d_in[2];
    const int*   tgt_lens = (const int*)d_in[3];
    const float* W        = (const float*)d_in[4];
    const float* bias     = (const float*)d_in[5];

    float* nll = (float*)d_ws;                                    // 32 f32
    float* out = (float*)d_out;

    fused_kernel<<<B_DIM, 256, 0, stream>>>(pred, targets, in_lens, tgt_lens,
                                            W, bias, nll);
    finalize_kernel<<<1, 64, 0, stream>>>(nll, out);
}

// Round 20
// 95.622 us; speedup vs baseline: 3.2353x; 3.2353x over previous
//
#include <hip/hip_runtime.h>
#include <hip/hip_bf16.h>
#include <cstdint>
#include <math.h>

#define B_DIM 32
#define T_DIM 1000
#define D_DIM 768
#define V_DIM 31
#define L_DIM 200
#define S_DIM 401      // 2L+1 CTC states
#define S_PAD 512      // 2 waves x 64 lanes x 4 states
#define VSTRIDE 32     // padded prob-row stride: 32 floats = 128 B

typedef __bf16 bf16x8 __attribute__((ext_vector_type(8)));
typedef float  f32x16 __attribute__((ext_vector_type(16)));
typedef float  f32x2  __attribute__((ext_vector_type(2)));
typedef __attribute__((address_space(3))) float lds_float;

#define SB() __builtin_amdgcn_sched_barrier(0)

// Wave-wide shift-up-by-1 via DPP WAVE_SHR1 (0x138): pure VALU. Lane 0 -> 0.
__device__ __forceinline__ float shup1_f(float x) {
    int r = __builtin_amdgcn_update_dpp(0, __float_as_int(x), 0x138, 0xF, 0xF, true);
    return __int_as_float(r);
}
__device__ __forceinline__ int shup1_i(int x) {
    return __builtin_amdgcn_update_dpp(0, x, 0x138, 0xF, 0xF, true);
}

// ---------------------------------------------------------------------------
// Kernel 1: logits = pred @ W^T + b via MFMA bf16, probs = softmax -> ws.
// 2-row-tile version: 64 rows/block, each wave runs TWO MFMAs per k-tile
// sharing one B-fragment (halves B traffic/cvt, doubles A-load concurrency).
// Epilogue: stride-33 padded red[] (conflict-free scalar access), softmax
// across all 64 lanes of wave0.
// ---------------------------------------------------------------------------
__global__ __launch_bounds__(256) void head_softmax_kernel(
    const float* __restrict__ pred,
    const float* __restrict__ W,
    const float* __restrict__ bias,
    float* __restrict__ probs)
{
    __shared__ float red[3][64][33];   // waves 1..3 partials, padded (25.3 KB)
    __shared__ float sm2[64][33];      // transpose, padded (8.4 KB)
    const int tid  = threadIdx.x;
    const int lane = tid & 63;
    const int w    = __builtin_amdgcn_readfirstlane(tid >> 6);  // K segment
    const int col  = lane & 31;
    const int h    = lane >> 5;
    const int row  = blockIdx.x * 64 + col;     // grid = 500 exactly
    const int vc   = (col < V_DIM) ? col : (V_DIM - 1);  // clamp pad col

    const float* pA0 = pred + (size_t)row * D_DIM + w * 192 + 8 * h;
    const float* pA1 = pA0 + (size_t)32 * D_DIM;
    const float* pB  = W + (size_t)vc * D_DIM + w * 192 + 8 * h;

    f32x16 acc0, acc1;
#pragma unroll
    for (int i = 0; i < 16; ++i) { acc0[i] = 0.f; acc1[i] = 0.f; }

#pragma unroll
    for (int kt = 0; kt < 12; ++kt) {
        const float4 x00 = *reinterpret_cast<const float4*>(pA0 + kt * 16);
        const float4 x01 = *reinterpret_cast<const float4*>(pA0 + kt * 16 + 4);
        const float4 x10 = *reinterpret_cast<const float4*>(pA1 + kt * 16);
        const float4 x11 = *reinterpret_cast<const float4*>(pA1 + kt * 16 + 4);
        const float4 b0  = *reinterpret_cast<const float4*>(pB + kt * 16);
        const float4 b1  = *reinterpret_cast<const float4*>(pB + kt * 16 + 4);
        bf16x8 af0, af1, bfr;
        af0[0] = (__bf16)x00.x; af0[1] = (__bf16)x00.y;
        af0[2] = (__bf16)x00.z; af0[3] = (__bf16)x00.w;
        af0[4] = (__bf16)x01.x; af0[5] = (__bf16)x01.y;
        af0[6] = (__bf16)x01.z; af0[7] = (__bf16)x01.w;
        af1[0] = (__bf16)x10.x; af1[1] = (__bf16)x10.y;
        af1[2] = (__bf16)x10.z; af1[3] = (__bf16)x10.w;
        af1[4] = (__bf16)x11.x; af1[5] = (__bf16)x11.y;
        af1[6] = (__bf16)x11.z; af1[7] = (__bf16)x11.w;
        bfr[0] = (__bf16)b0.x; bfr[1] = (__bf16)b0.y;
        bfr[2] = (__bf16)b0.z; bfr[3] = (__bf16)b0.w;
        bfr[4] = (__bf16)b1.x; bfr[5] = (__bf16)b1.y;
        bfr[6] = (__bf16)b1.z; bfr[7] = (__bf16)b1.w;
        acc0 = __builtin_amdgcn_mfma_f32_32x32x16_bf16(af0, bfr, acc0, 0, 0, 0);
        acc1 = __builtin_amdgcn_mfma_f32_32x32x16_bf16(af1, bfr, acc1, 0, 0, 0);
    }

    if (w > 0) {
#pragma unroll
        for (int i = 0; i < 16; ++i) {
            red[w - 1][lane][i]      = acc0[i];
            red[w - 1][lane][16 + i] = acc1[i];
        }
    }
    __syncthreads();
    if (w == 0) {
#pragma unroll
        for (int i = 0; i < 16; ++i) {
            acc0[i] += red[0][lane][i] + red[1][lane][i] + red[2][lane][i];
            acc1[i] += red[0][lane][16 + i] + red[1][lane][16 + i] + red[2][lane][16 + i];
        }
#pragma unroll
        for (int r = 0; r < 16; ++r) {
            const int rl = (r & 3) + 8 * (r >> 2) + 4 * h;
            sm2[rl][col]      = acc0[r];
            sm2[32 + rl][col] = acc1[r];
        }
        // all 64 lanes: softmax of block-row `lane`
        float lg[V_DIM];
        float m = -1e30f;
#pragma unroll
        for (int v = 0; v < V_DIM; ++v) {
            lg[v] = sm2[lane][v] + bias[v];
            m = fmaxf(m, lg[v]);
        }
        float e[32];
        float s = 0.f;
#pragma unroll
        for (int v = 0; v < V_DIM; ++v) { e[v] = __expf(lg[v] - m); s += e[v]; }
        const float inv = 1.0f / s;
#pragma unroll
        for (int v = 0; v < V_DIM; ++v) e[v] *= inv;
        e[31] = 0.f;
        float* op = probs + (size_t)(blockIdx.x * 64 + lane) * VSTRIDE;
#pragma unroll
        for (int q = 0; q < 8; ++q)
            *reinterpret_cast<float4*>(op + q * 4) =
                *reinterpret_cast<float4*>(&e[q * 4]);
    }
}

// --- asm helpers (counted waits; rule #18: sched_barrier after lgkmcnt) ----
#define WTn(n) do { asm volatile("s_waitcnt lgkmcnt(" #n ")" ::: "memory"); SB(); } while (0)
#define VM8()  asm volatile("s_waitcnt vmcnt(8)" ::: "memory")
#define BARR() do { asm volatile("s_waitcnt lgkmcnt(0)" ::: "memory"); SB(); \
                    asm volatile("s_barrier" ::: "memory"); SB(); } while (0)
#define RD3(G, off) do { \
    asm volatile("ds_read_b32 %0, %1 offset:" #off : "=v"(G[0]) : "v"(va[0])); \
    asm volatile("ds_read_b32 %0, %1 offset:" #off : "=v"(G[1]) : "v"(va[1])); \
    asm volatile("ds_read_b32 %0, %1 offset:" #off : "=v"(G[2]) : "v"(va[2])); } while (0)
#define RDE(E, base, off) \
    asm volatile("ds_read_b64 %0, %1 offset:" #off : "=v"(E) : "v"(base))
#define WB(o0, o1) \
    asm volatile("ds_write2_b32 %0, %1, %2 offset0:" #o0 " offset1:" #o1 \
                 :: "v"(wcur), "v"(a[3]), "v"(z2) : "memory")

// ---------------------------------------------------------------------------
// Kernel 2: CTC forward recursion, linear domain, pow2 renorm every 2 steps.
// TWO waves per batch, skewed pipeline: wave0 = states 0..255 (leads by one
// 16-step chunk, DMA-stages probs, writes boundary (a255,z2) per step);
// wave1 = states 256..511 (trails one chunk, consumes boundary entries with
// exact per-step pow2 rescale). One raw s_barrier per chunk (no vmcnt drain).
// Decoy boundary writes stride-4 (banks stride-1, conflict-free).
// ---------------------------------------------------------------------------
__global__ __launch_bounds__(128, 1) void ctc_alpha_kernel(
    const float* __restrict__ probs,
    const int* __restrict__ targets,
    const int* __restrict__ in_lens,
    const int* __restrict__ tgt_lens,
    float* __restrict__ out_nll)
{
    __shared__ float lbuf[4][16][VSTRIDE];          // 8 KB, slot = chunk%4
    __shared__ __align__(8) float bndb[3][16][2];   // boundary ring (a255, zbits)
    __shared__ float trash[256];                    // decoy for lane!=63 writes
    __shared__ float sal[S_PAD];

    const int b    = blockIdx.x;
    const int tid  = threadIdx.x;
    const int lane = tid & 63;
    const int w    = __builtin_amdgcn_readfirstlane(tid >> 6);
    const int Tin  = in_lens[b];
    const int tl   = tgt_lens[b];
    const int* tgt = targets + b * L_DIM;
    const float* __restrict__ prow = probs + (size_t)b * T_DIM * VSTRIDE;

    const int NS = Tin - 1;        // steps t = 1..Tin-1
    const int F  = NS >> 4;        // full chunks
    const int R  = NS & 15;        // remainder steps

    // per-lane labels (2 odd states) + skip masks; pad states inert
    int k0 = (w ? 128 : 0) + 2 * lane;
    int k1 = k0 + 1;
    if (k0 > L_DIM - 1) k0 = L_DIM - 1;
    if (k1 > L_DIM - 1) k1 = L_DIM - 1;
    const int loff0 = tgt[k0];
    const int loff1 = tgt[k1];
    const int k0m   = (k0 > 0) ? k0 - 1 : 0;
    const float m20 = (w == 0 && lane == 0) ? 0.f : ((loff0 != tgt[k0m]) ? 1.f : 0.f);
    const float m21 = (loff1 != tgt[k1 - 1]) ? 1.f : 0.f;

    const uint32_t lb_base  = (uint32_t)(uintptr_t)(lds_float*)&lbuf[0][0][0];
    const uint32_t bnd_base = (uint32_t)(uintptr_t)(lds_float*)&bndb[0][0][0];
    const uint32_t tr_base  = (uint32_t)(uintptr_t)(lds_float*)&trash[0];

    float a[4] = {0.f, 0.f, 0.f, 0.f};
    int   z2 = 0;
    const float fz = (lane == 0) ? 0.f : 1.0f;
    float f = fz;

    uint32_t va[3];
    va[0] = lb_base + (uint32_t)(loff0 * 4);
    va[1] = lb_base + (uint32_t)(loff1 * 4);
    va[2] = lb_base;

    float GA[3], GB[3], GC[3], GD[3];

    if (w == 0) {
        // ============================ WAVE 0 ============================
        if (lane == 0) {            // t=0 init: states 0,1
            a[0] = prow[0];
            a[1] = prow[loff0];
        }
        // stride-4 decoy: banks (lane+off)%32 -> stride-1, conflict-free
        const uint32_t wsel = (lane == 63) ? bnd_base : (tr_base + (uint32_t)(lane * 4));
        uint32_t wcur = wsel;
        {   // initial boundary entry (chunk -1, entry 15) = slot2,e15: zeros
            const uint32_t winit = wsel + 256;
            asm volatile("ds_write2_b32 %0, %1, %2 offset0:30 offset1:31"
                         :: "v"(winit), "v"(a[3]), "v"(z2) : "memory");
        }

        auto ISSUE = [&](uint32_t slotbyte, int tbase) {
#pragma unroll
            for (int i = 0; i < 8; ++i) {
                int rowb = tbase + 2 * i;
                if (rowb > T_DIM - 2) rowb = T_DIM - 2;
                const float* src = prow + (size_t)rowb * VSTRIDE + lane;
                float* dst = &lbuf[0][0][0] + slotbyte / 4 + i * 64;
                __builtin_amdgcn_global_load_lds(
                    (const __attribute__((address_space(1))) void*)src,
                    (__attribute__((address_space(3))) void*)dst, 4, 0, 0);
            }
        };
        auto ST0 = [&](const float (&G)[3]) {
            const float s3p = shup1_f(a[3]);
            const float am1 = s3p * f;
            const float n0 = (a[0] + am1) * G[2];
            const float n1 = (a[1] + a[0] + m20 * am1) * G[0];
            const float n2 = (a[2] + a[1]) * G[2];
            const float n3 = (a[3] + a[2] + m21 * a[1]) * G[1];
            a[0] = n0; a[1] = n1; a[2] = n2; a[3] = n3;
        };
        auto REN0 = [&]() {
            const float mx = fmaxf(fmaxf(a[0], a[1]), fmaxf(a[2], a[3]));
            int e; (void)frexpf(mx, &e);
            const int zc = z2 + e;
            const int zp = shup1_i(zc);
            z2 = (mx > 0.f) ? zc : zp;
            a[0] = ldexpf(a[0], -e); a[1] = ldexpf(a[1], -e);
            a[2] = ldexpf(a[2], -e); a[3] = ldexpf(a[3], -e);
            const int dz = zp - z2;
            f = ldexpf(fz, dz);
        };

        uint32_t ro = 0, dsto = 4096;
        int tbi = 33;
        ISSUE(0, 1);
        ISSUE(2048, 17);
        VM8();
        RD3(GA, 0);
        RD3(GB, 128);

        for (int s = 0; s < F; ++s) {
            RD3(GC, 256);  WTn(8); ST0(GA);         WB(0, 1);
            RD3(GD, 384);  WTn(8); ST0(GB); REN0(); WB(2, 3);
            RD3(GA, 512);  WTn(8); ST0(GC);         WB(4, 5);
            RD3(GB, 640);  WTn(8); ST0(GD); REN0(); WB(6, 7);
            RD3(GC, 768);  WTn(8); ST0(GA);         WB(8, 9);
            RD3(GD, 896);  WTn(8); ST0(GB); REN0(); WB(10, 11);
            RD3(GA, 1024); WTn(8); ST0(GC);         WB(12, 13);
            RD3(GB, 1152); WTn(8); ST0(GD); REN0(); WB(14, 15);
            RD3(GC, 1280); WTn(8); ST0(GA);         WB(16, 17);
            RD3(GD, 1408); WTn(8); ST0(GB); REN0(); WB(18, 19);
            RD3(GA, 1536); WTn(8); ST0(GC);         WB(20, 21);
            RD3(GB, 1664); WTn(8); ST0(GD); REN0(); WB(22, 23);
            RD3(GC, 1792); WTn(8); ST0(GA);         WB(24, 25);
            RD3(GD, 1920); WTn(8); ST0(GB); REN0(); WB(26, 27);
            // advance gather ring to next slot; keep DMA pipeline full
            ro = (ro + 2048u) & 8191u;
            va[0] = lb_base + ro + (uint32_t)(loff0 * 4);
            va[1] = lb_base + ro + (uint32_t)(loff1 * 4);
            va[2] = lb_base + ro;
            ISSUE(dsto, tbi);
            dsto = (dsto + 2048u) & 8191u;
            tbi += 16;
            VM8();
            RD3(GA, 0);    WTn(8); ST0(GC);         WB(28, 29);
            RD3(GB, 128);  WTn(8); ST0(GD); REN0(); WB(30, 31);
            wcur = (wcur == wsel + 256u) ? wsel : wcur + 128u;
            BARR();
        }
        // partial superstep F: R steps (GA,GB preloaded rows 0,1 of slot F)
        if (R > 0)  { RD3(GC, 256);  WTn(8); ST0(GA);         WB(0, 1); }
        if (R > 1)  { RD3(GD, 384);  WTn(8); ST0(GB); REN0(); WB(2, 3); }
        if (R > 2)  { RD3(GA, 512);  WTn(8); ST0(GC);         WB(4, 5); }
        if (R > 3)  { RD3(GB, 640);  WTn(8); ST0(GD); REN0(); WB(6, 7); }
        if (R > 4)  { RD3(GC, 768);  WTn(8); ST0(GA);         WB(8, 9); }
        if (R > 5)  { RD3(GD, 896);  WTn(8); ST0(GB); REN0(); WB(10, 11); }
        if (R > 6)  { RD3(GA, 1024); WTn(8); ST0(GC);         WB(12, 13); }
        if (R > 7)  { RD3(GB, 1152); WTn(8); ST0(GD); REN0(); WB(14, 15); }
        if (R > 8)  { RD3(GC, 1280); WTn(8); ST0(GA);         WB(16, 17); }
        if (R > 9)  { RD3(GD, 1408); WTn(8); ST0(GB); REN0(); WB(18, 19); }
        if (R > 10) { RD3(GA, 1536); WTn(8); ST0(GC);         WB(20, 21); }
        if (R > 11) { RD3(GB, 1664); WTn(8); ST0(GD); REN0(); WB(22, 23); }
        if (R > 12) { RD3(GC, 1792); WTn(8); ST0(GA);         WB(24, 25); }
        if (R > 13) { RD3(GD, 1920); WTn(8); ST0(GB); REN0(); WB(26, 27); }
        if (R > 14) { WTn(4); ST0(GC); WB(28, 29); }
        BARR();       // final barrier (count = F+1 on both waves)
        return;
    } else {
        // ============================ WAVE 1 ============================
        const float fbz = (lane == 0) ? 1.0f : 0.f;
        f32x2 EA, EB, EC, ED;

        auto ST1 = [&](const float (&G)[3], const f32x2& E) {
            const float s3p = shup1_f(a[3]);
            float am1 = s3p * f;
            const int dzb = __float_as_int(E[1]) - z2;
            am1 = fmaf(E[0], ldexpf(fbz, dzb), am1);
            const float n0 = (a[0] + am1) * G[2];
            const float n1 = (a[1] + a[0] + m20 * am1) * G[0];
            const float n2 = (a[2] + a[1]) * G[2];
            const float n3 = (a[3] + a[2] + m21 * a[1]) * G[1];
            a[0] = n0; a[1] = n1; a[2] = n2; a[3] = n3;
        };
        auto REN1 = [&](const f32x2& E) {
            const float mx = fmaxf(fmaxf(a[0], a[1]), fmaxf(a[2], a[3]));
            int e; (void)frexpf(mx, &e);
            const int zc = z2 + e;
            int zp = shup1_i(zc);
            zp = (lane == 0) ? __float_as_int(E[1]) : zp;   // adopt across waves
            z2 = (mx > 0.f) ? zc : zp;
            a[0] = ldexpf(a[0], -e); a[1] = ldexpf(a[1], -e);
            a[2] = ldexpf(a[2], -e); a[3] = ldexpf(a[3], -e);
            const int dz = zp - z2;
            f = ldexpf(fz, dz);
        };

        uint32_t ro = 0;
        uint32_t cb = bnd_base, pb = bnd_base + 256u;
        BARR();   // superstep 0 (idle)
        for (int c = 0; c < F; ++c) {
            RD3(GA, 0);    RDE(EA, pb, 120);
            RD3(GB, 128);  RDE(EB, cb, 0);
            WTn(0);
            RD3(GC, 256);  RDE(EC, cb, 8);   WTn(8); ST1(GA, EA);
            RD3(GD, 384);  RDE(ED, cb, 16);  WTn(8); ST1(GB, EB); REN1(EB);
            RD3(GA, 512);  RDE(EA, cb, 24);  WTn(8); ST1(GC, EC);
            RD3(GB, 640);  RDE(EB, cb, 32);  WTn(8); ST1(GD, ED); REN1(ED);
            RD3(GC, 768);  RDE(EC, cb, 40);  WTn(8); ST1(GA, EA);
            RD3(GD, 896);  RDE(ED, cb, 48);  WTn(8); ST1(GB, EB); REN1(EB);
            RD3(GA, 1024); RDE(EA, cb, 56);  WTn(8); ST1(GC, EC);
            RD3(GB, 1152); RDE(EB, cb, 64);  WTn(8); ST1(GD, ED); REN1(ED);
            RD3(GC, 1280); RDE(EC, cb, 72);  WTn(8); ST1(GA, EA);
            RD3(GD, 1408); RDE(ED, cb, 80);  WTn(8); ST1(GB, EB); REN1(EB);
            RD3(GA, 1536); RDE(EA, cb, 88);  WTn(8); ST1(GC, EC);
            RD3(GB, 1664); RDE(EB, cb, 96);  WTn(8); ST1(GD, ED); REN1(ED);
            RD3(GC, 1792); RDE(EC, cb, 104); WTn(8); ST1(GA, EA);
            RD3(GD, 1920); RDE(ED, cb, 112); WTn(8); ST1(GB, EB); REN1(EB);
            WTn(4); ST1(GC, EC);
            WTn(0); ST1(GD, ED); REN1(ED);
            ro = (ro + 2048u) & 8191u;
            va[0] = lb_base + ro + (uint32_t)(loff0 * 4);
            va[1] = lb_base + ro + (uint32_t)(loff1 * 4);
            va[2] = lb_base + ro;
            pb = cb;
            cb = (cb == bnd_base + 256u) ? bnd_base : cb + 128u;
            BARR();
        }
        // free-run: chunk F (R steps); all data written before final barrier
        if (R > 0) {
            RD3(GA, 0);   RDE(EA, pb, 120);
            RD3(GB, 128); RDE(EB, cb, 0);
            WTn(0);
            RD3(GC, 256); RDE(EC, cb, 8); WTn(8); ST1(GA, EA);
        }
        if (R > 1)  { RD3(GD, 384);  RDE(ED, cb, 16);  WTn(8); ST1(GB, EB); REN1(EB); }
        if (R > 2)  { RD3(GA, 512);  RDE(EA, cb, 24);  WTn(8); ST1(GC, EC); }
        if (R > 3)  { RD3(GB, 640);  RDE(EB, cb, 32);  WTn(8); ST1(GD, ED); REN1(ED); }
        if (R > 4)  { RD3(GC, 768);  RDE(EC, cb, 40);  WTn(8); ST1(GA, EA); }
        if (R > 5)  { RD3(GD, 896);  RDE(ED, cb, 48);  WTn(8); ST1(GB, EB); REN1(EB); }
        if (R > 6)  { RD3(GA, 1024); RDE(EA, cb, 56);  WTn(8); ST1(GC, EC); }
        if (R > 7)  { RD3(GB, 1152); RDE(EB, cb, 64);  WTn(8); ST1(GD, ED); REN1(ED); }
        if (R > 8)  { RD3(GC, 1280); RDE(EC, cb, 72);  WTn(8); ST1(GA, EA); }
        if (R > 9)  { RD3(GD, 1408); RDE(ED, cb, 80);  WTn(8); ST1(GB, EB); REN1(EB); }
        if (R > 10) { RD3(GA, 1536); RDE(EA, cb, 88);  WTn(8); ST1(GC, EC); }
        if (R > 11) { RD3(GB, 1664); RDE(EB, cb, 96);  WTn(8); ST1(GD, ED); REN1(ED); }
        if (R > 12) { RD3(GC, 1792); RDE(EC, cb, 104); WTn(8); ST1(GA, EA); }
        if (R > 13) { RD3(GD, 1920); RDE(ED, cb, 112); WTn(8); ST1(GB, EB); REN1(EB); }
        if (R > 14) { WTn(4); ST1(GC, EC); }
        WTn(0);

        // absolute log-alpha for states 256..511; final states are >= 299
        const float zln2 = (float)z2 * 0.69314718055994530942f;
        sal[256 + 4 * lane + 0] = __logf(a[0]) + zln2;
        sal[256 + 4 * lane + 1] = __logf(a[1]) + zln2;
        sal[256 + 4 * lane + 2] = __logf(a[2]) + zln2;
        sal[256 + 4 * lane + 3] = __logf(a[3]) + zln2;
        asm volatile("s_waitcnt lgkmcnt(0)" ::: "memory");
        SB();
        if (lane == 0) {
            const float x0 = sal[2 * tl - 1];
            const float x1 = sal[2 * tl];
            const float m  = fmaxf(x0, x1);
            float nll = -(m + __logf(__expf(x0 - m) + __expf(x1 - m)));
            if (!(nll < 1e29f)) nll = 0.f;       // zero_infinity (inf/NaN too)
            out_nll[b] = nll / (float)tl;
        }
    }
}

// ---------------------------------------------------------------------------
// Kernel 3: deterministic mean over B
// ---------------------------------------------------------------------------
__global__ void finalize_kernel(const float* __restrict__ nll, float* __restrict__ out)
{
    if (threadIdx.x == 0 && blockIdx.x == 0) {
        float s = 0.f;
        for (int i = 0; i < B_DIM; ++i) s += nll[i];
        out[0] = s * (1.0f / (float)B_DIM);
    }
}

extern "C" void kernel_launch(void* const* d_in, const int* in_sizes, int n_in,
                              void* d_out, int out_size, void* d_ws, size_t ws_size,
                              hipStream_t stream)
{
    const float* pred     = (const float*)d_in[0];
    const int*   targets  = (const int*)d_in[1];
    const int*   in_lens  = (const int*)d_in[2];
    const int*   tgt_lens = (const int*)d_in[3];
    const float* W        = (const float*)d_in[4];
    const float* bias     = (const float*)d_in[5];

    float* probs = (float*)d_ws;                                  // 32*1000*32 f32 = 4.1 MB
    float* nll   = probs + (size_t)B_DIM * T_DIM * VSTRIDE;       // 32 f32
    float* out   = (float*)d_out;

    head_softmax_kernel<<<(B_DIM * T_DIM) / 64, 256, 0, stream>>>(pred, W, bias, probs);
    ctc_alpha_kernel<<<B_DIM, 128, 0, stream>>>(probs, targets, in_lens, tgt_lens, nll);
    finalize_kernel<<<1, 64, 0, stream>>>(nll, out);
}

// Round 21
// 94.582 us; speedup vs baseline: 3.2709x; 1.0110x over previous
//
#include <hip/hip_runtime.h>
#include <hip/hip_bf16.h>
#include <cstdint>
#include <math.h>

#define B_DIM 32
#define T_DIM 1000
#define D_DIM 768
#define V_DIM 31
#define L_DIM 200
#define S_DIM 401      // 2L+1 CTC states
#define S_PAD 512      // 2 waves x 64 lanes x 4 states
#define VSTRIDE 32     // padded prob-row stride: 32 floats = 128 B

typedef __bf16 bf16x8 __attribute__((ext_vector_type(8)));
typedef float  f32x16 __attribute__((ext_vector_type(16)));
typedef float  f32x4  __attribute__((ext_vector_type(4)));
typedef __attribute__((address_space(3))) float lds_float;

#define SB() __builtin_amdgcn_sched_barrier(0)

// Wave-wide shift-up-by-1 via DPP WAVE_SHR1 (0x138): pure VALU. Lane 0 -> 0.
__device__ __forceinline__ float shup1_f(float x) {
    int r = __builtin_amdgcn_update_dpp(0, __float_as_int(x), 0x138, 0xF, 0xF, true);
    return __int_as_float(r);
}
__device__ __forceinline__ int shup1_i(int x) {
    return __builtin_amdgcn_update_dpp(0, x, 0x138, 0xF, 0xF, true);
}

// ---------------------------------------------------------------------------
// Kernel 1: logits = pred @ W^T + b via MFMA bf16, probs = softmax -> ws.
// (r17 version, verified, ~26 us.)
// ---------------------------------------------------------------------------
__global__ __launch_bounds__(256) void head_softmax_kernel(
    const float* __restrict__ pred,
    const float* __restrict__ W,
    const float* __restrict__ bias,
    float* __restrict__ probs)
{
    __shared__ float red[3][64][33];   // waves 1..3 partials, padded (25.3 KB)
    __shared__ float sm2[64][33];      // transpose, padded (8.4 KB)
    const int tid  = threadIdx.x;
    const int lane = tid & 63;
    const int w    = __builtin_amdgcn_readfirstlane(tid >> 6);  // K segment
    const int col  = lane & 31;
    const int h    = lane >> 5;
    const int row  = blockIdx.x * 64 + col;     // grid = 500 exactly
    const int vc   = (col < V_DIM) ? col : (V_DIM - 1);  // clamp pad col

    const float* pA0 = pred + (size_t)row * D_DIM + w * 192 + 8 * h;
    const float* pA1 = pA0 + (size_t)32 * D_DIM;
    const float* pB  = W + (size_t)vc * D_DIM + w * 192 + 8 * h;

    f32x16 acc0, acc1;
#pragma unroll
    for (int i = 0; i < 16; ++i) { acc0[i] = 0.f; acc1[i] = 0.f; }

#pragma unroll
    for (int kt = 0; kt < 12; ++kt) {
        const float4 x00 = *reinterpret_cast<const float4*>(pA0 + kt * 16);
        const float4 x01 = *reinterpret_cast<const float4*>(pA0 + kt * 16 + 4);
        const float4 x10 = *reinterpret_cast<const float4*>(pA1 + kt * 16);
        const float4 x11 = *reinterpret_cast<const float4*>(pA1 + kt * 16 + 4);
        const float4 b0  = *reinterpret_cast<const float4*>(pB + kt * 16);
        const float4 b1  = *reinterpret_cast<const float4*>(pB + kt * 16 + 4);
        bf16x8 af0, af1, bfr;
        af0[0] = (__bf16)x00.x; af0[1] = (__bf16)x00.y;
        af0[2] = (__bf16)x00.z; af0[3] = (__bf16)x00.w;
        af0[4] = (__bf16)x01.x; af0[5] = (__bf16)x01.y;
        af0[6] = (__bf16)x01.z; af0[7] = (__bf16)x01.w;
        af1[0] = (__bf16)x10.x; af1[1] = (__bf16)x10.y;
        af1[2] = (__bf16)x10.z; af1[3] = (__bf16)x10.w;
        af1[4] = (__bf16)x11.x; af1[5] = (__bf16)x11.y;
        af1[6] = (__bf16)x11.z; af1[7] = (__bf16)x11.w;
        bfr[0] = (__bf16)b0.x; bfr[1] = (__bf16)b0.y;
        bfr[2] = (__bf16)b0.z; bfr[3] = (__bf16)b0.w;
        bfr[4] = (__bf16)b1.x; bfr[5] = (__bf16)b1.y;
        bfr[6] = (__bf16)b1.z; bfr[7] = (__bf16)b1.w;
        acc0 = __builtin_amdgcn_mfma_f32_32x32x16_bf16(af0, bfr, acc0, 0, 0, 0);
        acc1 = __builtin_amdgcn_mfma_f32_32x32x16_bf16(af1, bfr, acc1, 0, 0, 0);
    }

    if (w > 0) {
#pragma unroll
        for (int i = 0; i < 16; ++i) {
            red[w - 1][lane][i]      = acc0[i];
            red[w - 1][lane][16 + i] = acc1[i];
        }
    }
    __syncthreads();
    if (w == 0) {
#pragma unroll
        for (int i = 0; i < 16; ++i) {
            acc0[i] += red[0][lane][i] + red[1][lane][i] + red[2][lane][i];
            acc1[i] += red[0][lane][16 + i] + red[1][lane][16 + i] + red[2][lane][16 + i];
        }
#pragma unroll
        for (int r = 0; r < 16; ++r) {
            const int rl = (r & 3) + 8 * (r >> 2) + 4 * h;
            sm2[rl][col]      = acc0[r];
            sm2[32 + rl][col] = acc1[r];
        }
        // all 64 lanes: softmax of block-row `lane`
        float lg[V_DIM];
        float m = -1e30f;
#pragma unroll
        for (int v = 0; v < V_DIM; ++v) {
            lg[v] = sm2[lane][v] + bias[v];
            m = fmaxf(m, lg[v]);
        }
        float e[32];
        float s = 0.f;
#pragma unroll
        for (int v = 0; v < V_DIM; ++v) { e[v] = __expf(lg[v] - m); s += e[v]; }
        const float inv = 1.0f / s;
#pragma unroll
        for (int v = 0; v < V_DIM; ++v) e[v] *= inv;
        e[31] = 0.f;
        float* op = probs + (size_t)(blockIdx.x * 64 + lane) * VSTRIDE;
#pragma unroll
        for (int q = 0; q < 8; ++q)
            *reinterpret_cast<float4*>(op + q * 4) =
                *reinterpret_cast<float4*>(&e[q * 4]);
    }
}

// --- asm helpers (counted waits; rule #18: sched_barrier after lgkmcnt) ----
#define WTn(n) do { asm volatile("s_waitcnt lgkmcnt(" #n ")" ::: "memory"); SB(); } while (0)
#define VM8()  asm volatile("s_waitcnt vmcnt(8)" ::: "memory")
#define BARR() do { asm volatile("s_waitcnt lgkmcnt(0)" ::: "memory"); SB(); \
                    asm volatile("s_barrier" ::: "memory"); SB(); } while (0)
#define RD3(G, off) do { \
    asm volatile("ds_read_b32 %0, %1 offset:" #off : "=v"(G[0]) : "v"(va[0])); \
    asm volatile("ds_read_b32 %0, %1 offset:" #off : "=v"(G[1]) : "v"(va[1])); \
    asm volatile("ds_read_b32 %0, %1 offset:" #off : "=v"(G[2]) : "v"(va[2])); } while (0)
#define RDQ(Q, off) \
    asm volatile("ds_read_b128 %0, %1 offset:" #off : "=v"(Q) : "v"(cbv))
#define WB(o0, o1) \
    asm volatile("ds_write2_b32 %0, %1, %2 offset0:" #o0 " offset1:" #o1 \
                 :: "v"(wcur), "v"(a[3]), "v"(z2) : "memory")

// ---------------------------------------------------------------------------
// Kernel 2: CTC forward recursion, linear domain, pow2 renorm every 2 steps.
// TWO waves per batch, skewed pipeline (r17 structure, verified). Wave1 now
// batch-reads the 16 boundary entries per chunk as 8x ds_read_b128 (entry 15
// carried in registers to the next chunk) and runs at s_setprio(1): the
// critical wave's per-step DS stream shrinks from 4 to 3 events.
// ---------------------------------------------------------------------------
__global__ __launch_bounds__(128, 1) void ctc_alpha_kernel(
    const float* __restrict__ probs,
    const int* __restrict__ targets,
    const int* __restrict__ in_lens,
    const int* __restrict__ tgt_lens,
    float* __restrict__ out_nll)
{
    __shared__ float lbuf[4][16][VSTRIDE];           // 8 KB, slot = chunk%4
    __shared__ __align__(16) float bndb[3][16][2];   // boundary ring (a255, zbits)
    __shared__ float trash[256];                     // decoy for lane!=63 writes
    __shared__ float sal[S_PAD];

    const int b    = blockIdx.x;
    const int tid  = threadIdx.x;
    const int lane = tid & 63;
    const int w    = __builtin_amdgcn_readfirstlane(tid >> 6);
    const int Tin  = in_lens[b];
    const int tl   = tgt_lens[b];
    const int* tgt = targets + b * L_DIM;
    const float* __restrict__ prow = probs + (size_t)b * T_DIM * VSTRIDE;

    const int NS = Tin - 1;        // steps t = 1..Tin-1
    const int F  = NS >> 4;        // full chunks
    const int R  = NS & 15;        // remainder steps

    // per-lane labels (2 odd states) + skip masks; pad states inert
    int k0 = (w ? 128 : 0) + 2 * lane;
    int k1 = k0 + 1;
    if (k0 > L_DIM - 1) k0 = L_DIM - 1;
    if (k1 > L_DIM - 1) k1 = L_DIM - 1;
    const int loff0 = tgt[k0];
    const int loff1 = tgt[k1];
    const int k0m   = (k0 > 0) ? k0 - 1 : 0;
    const float m20 = (w == 0 && lane == 0) ? 0.f : ((loff0 != tgt[k0m]) ? 1.f : 0.f);
    const float m21 = (loff1 != tgt[k1 - 1]) ? 1.f : 0.f;

    const uint32_t lb_base  = (uint32_t)(uintptr_t)(lds_float*)&lbuf[0][0][0];
    const uint32_t bnd_base = (uint32_t)(uintptr_t)(lds_float*)&bndb[0][0][0];
    const uint32_t tr_base  = (uint32_t)(uintptr_t)(lds_float*)&trash[0];

    float a[4] = {0.f, 0.f, 0.f, 0.f};
    int   z2 = 0;
    const float fz = (lane == 0) ? 0.f : 1.0f;
    float f = fz;

    uint32_t va[3];
    va[0] = lb_base + (uint32_t)(loff0 * 4);
    va[1] = lb_base + (uint32_t)(loff1 * 4);
    va[2] = lb_base;

    float GA[3], GB[3], GC[3], GD[3];

    if (w == 0) {
        // ============================ WAVE 0 ============================
        if (lane == 0) {            // t=0 init: states 0,1
            a[0] = prow[0];
            a[1] = prow[loff0];
        }
        // stride-4 decoy: banks (lane+off)%32 -> stride-1, conflict-free
        const uint32_t wsel = (lane == 63) ? bnd_base : (tr_base + (uint32_t)(lane * 4));
        uint32_t wcur = wsel;
        {   // initial boundary entry (chunk -1, entry 15) = slot2,e15: zeros
            const uint32_t winit = wsel + 256;
            asm volatile("ds_write2_b32 %0, %1, %2 offset0:30 offset1:31"
                         :: "v"(winit), "v"(a[3]), "v"(z2) : "memory");
        }

        auto ISSUE = [&](uint32_t slotbyte, int tbase) {
#pragma unroll
            for (int i = 0; i < 8; ++i) {
                int rowb = tbase + 2 * i;
                if (rowb > T_DIM - 2) rowb = T_DIM - 2;
                const float* src = prow + (size_t)rowb * VSTRIDE + lane;
                float* dst = &lbuf[0][0][0] + slotbyte / 4 + i * 64;
                __builtin_amdgcn_global_load_lds(
                    (const __attribute__((address_space(1))) void*)src,
                    (__attribute__((address_space(3))) void*)dst, 4, 0, 0);
            }
        };
        auto ST0 = [&](const float (&G)[3]) {
            const float s3p = shup1_f(a[3]);
            const float am1 = s3p * f;
            const float n0 = (a[0] + am1) * G[2];
            const float n1 = (a[1] + a[0] + m20 * am1) * G[0];
            const float n2 = (a[2] + a[1]) * G[2];
            const float n3 = (a[3] + a[2] + m21 * a[1]) * G[1];
            a[0] = n0; a[1] = n1; a[2] = n2; a[3] = n3;
        };
        auto REN0 = [&]() {
            const float mx = fmaxf(fmaxf(a[0], a[1]), fmaxf(a[2], a[3]));
            int e; (void)frexpf(mx, &e);
            const int zc = z2 + e;
            const int zp = shup1_i(zc);
            z2 = (mx > 0.f) ? zc : zp;
            a[0] = ldexpf(a[0], -e); a[1] = ldexpf(a[1], -e);
            a[2] = ldexpf(a[2], -e); a[3] = ldexpf(a[3], -e);
            const int dz = zp - z2;
            f = ldexpf(fz, dz);
        };

        uint32_t ro = 0, dsto = 4096;
        int tbi = 33;
        ISSUE(0, 1);
        ISSUE(2048, 17);
        VM8();
        RD3(GA, 0);
        RD3(GB, 128);

        for (int s = 0; s < F; ++s) {
            RD3(GC, 256);  WTn(8); ST0(GA);         WB(0, 1);
            RD3(GD, 384);  WTn(8); ST0(GB); REN0(); WB(2, 3);
            RD3(GA, 512);  WTn(8); ST0(GC);         WB(4, 5);
            RD3(GB, 640);  WTn(8); ST0(GD); REN0(); WB(6, 7);
            RD3(GC, 768);  WTn(8); ST0(GA);         WB(8, 9);
            RD3(GD, 896);  WTn(8); ST0(GB); REN0(); WB(10, 11);
            RD3(GA, 1024); WTn(8); ST0(GC);         WB(12, 13);
            RD3(GB, 1152); WTn(8); ST0(GD); REN0(); WB(14, 15);
            RD3(GC, 1280); WTn(8); ST0(GA);         WB(16, 17);
            RD3(GD, 1408); WTn(8); ST0(GB); REN0(); WB(18, 19);
            RD3(GA, 1536); WTn(8); ST0(GC);         WB(20, 21);
            RD3(GB, 1664); WTn(8); ST0(GD); REN0(); WB(22, 23);
            RD3(GC, 1792); WTn(8); ST0(GA);         WB(24, 25);
            RD3(GD, 1920); WTn(8); ST0(GB); REN0(); WB(26, 27);
            // advance gather ring to next slot; keep DMA pipeline full
            ro = (ro + 2048u) & 8191u;
            va[0] = lb_base + ro + (uint32_t)(loff0 * 4);
            va[1] = lb_base + ro + (uint32_t)(loff1 * 4);
            va[2] = lb_base + ro;
            ISSUE(dsto, tbi);
            dsto = (dsto + 2048u) & 8191u;
            tbi += 16;
            VM8();
            RD3(GA, 0);    WTn(8); ST0(GC);         WB(28, 29);
            RD3(GB, 128);  WTn(8); ST0(GD); REN0(); WB(30, 31);
            wcur = (wcur == wsel + 256u) ? wsel : wcur + 128u;
            BARR();
        }
        // partial superstep F: R steps (GA,GB preloaded rows 0,1 of slot F)
        if (R > 0)  { RD3(GC, 256);  WTn(8); ST0(GA);         WB(0, 1); }
        if (R > 1)  { RD3(GD, 384);  WTn(8); ST0(GB); REN0(); WB(2, 3); }
        if (R > 2)  { RD3(GA, 512);  WTn(8); ST0(GC);         WB(4, 5); }
        if (R > 3)  { RD3(GB, 640);  WTn(8); ST0(GD); REN0(); WB(6, 7); }
        if (R > 4)  { RD3(GC, 768);  WTn(8); ST0(GA);         WB(8, 9); }
        if (R > 5)  { RD3(GD, 896);  WTn(8); ST0(GB); REN0(); WB(10, 11); }
        if (R > 6)  { RD3(GA, 1024); WTn(8); ST0(GC);         WB(12, 13); }
        if (R > 7)  { RD3(GB, 1152); WTn(8); ST0(GD); REN0(); WB(14, 15); }
        if (R > 8)  { RD3(GC, 1280); WTn(8); ST0(GA);         WB(16, 17); }
        if (R > 9)  { RD3(GD, 1408); WTn(8); ST0(GB); REN0(); WB(18, 19); }
        if (R > 10) { RD3(GA, 1536); WTn(8); ST0(GC);         WB(20, 21); }
        if (R > 11) { RD3(GB, 1664); WTn(8); ST0(GD); REN0(); WB(22, 23); }
        if (R > 12) { RD3(GC, 1792); WTn(8); ST0(GA);         WB(24, 25); }
        if (R > 13) { RD3(GD, 1920); WTn(8); ST0(GB); REN0(); WB(26, 27); }
        if (R > 14) { WTn(4); ST0(GC); WB(28, 29); }
        BARR();       // final barrier (count = F+1 on both waves)
        return;
    } else {
        // ============================ WAVE 1 ============================
        __builtin_amdgcn_s_setprio(1);    // critical wave: bias arbitration
        const float fbz = (lane == 0) ? 1.0f : 0.f;
        f32x4 Q0, Q1, Q2, Q3, Q4, Q5, Q6, Q7;
        float epA = 0.f, epZ = 0.f;       // carried entry 15 (init = winit zeros)

        auto ST1 = [&](const float (&G)[3], float Ea, float Ez) {
            const float s3p = shup1_f(a[3]);
            float am1 = s3p * f;
            const int dzb = __float_as_int(Ez) - z2;
            am1 = fmaf(Ea, ldexpf(fbz, dzb), am1);
            const float n0 = (a[0] + am1) * G[2];
            const float n1 = (a[1] + a[0] + m20 * am1) * G[0];
            const float n2 = (a[2] + a[1]) * G[2];
            const float n3 = (a[3] + a[2] + m21 * a[1]) * G[1];
            a[0] = n0; a[1] = n1; a[2] = n2; a[3] = n3;
        };
        auto REN1 = [&](float Ez) {
            const float mx = fmaxf(fmaxf(a[0], a[1]), fmaxf(a[2], a[3]));
            int e; (void)frexpf(mx, &e);
            const int zc = z2 + e;
            int zp = shup1_i(zc);
            zp = (lane == 0) ? __float_as_int(Ez) : zp;   // adopt across waves
            z2 = (mx > 0.f) ? zc : zp;
            a[0] = ldexpf(a[0], -e); a[1] = ldexpf(a[1], -e);
            a[2] = ldexpf(a[2], -e); a[3] = ldexpf(a[3], -e);
            const int dz = zp - z2;
            f = ldexpf(fz, dz);
        };

        uint32_t ro = 0;
        uint32_t cbv = bnd_base;
        BARR();   // superstep 0 (idle)
        for (int c = 0; c < F; ++c) {
            RD3(GA, 0);
            RD3(GB, 128);
            RDQ(Q0, 0);  RDQ(Q1, 16); RDQ(Q2, 32); RDQ(Q3, 48);
            RDQ(Q4, 64); RDQ(Q5, 80); RDQ(Q6, 96); RDQ(Q7, 112);
            WTn(0);
            RD3(GC, 256);  WTn(6); ST1(GA, epA, epZ);
            RD3(GD, 384);  WTn(6); ST1(GB, Q0[0], Q0[1]); REN1(Q0[1]);
            RD3(GA, 512);  WTn(6); ST1(GC, Q0[2], Q0[3]);
            RD3(GB, 640);  WTn(6); ST1(GD, Q1[0], Q1[1]); REN1(Q1[1]);
            RD3(GC, 768);  WTn(6); ST1(GA, Q1[2], Q1[3]);
            RD3(GD, 896);  WTn(6); ST1(GB, Q2[0], Q2[1]); REN1(Q2[1]);
            RD3(GA, 1024); WTn(6); ST1(GC, Q2[2], Q2[3]);
            RD3(GB, 1152); WTn(6); ST1(GD, Q3[0], Q3[1]); REN1(Q3[1]);
            RD3(GC, 1280); WTn(6); ST1(GA, Q3[2], Q3[3]);
            RD3(GD, 1408); WTn(6); ST1(GB, Q4[0], Q4[1]); REN1(Q4[1]);
            RD3(GA, 1536); WTn(6); ST1(GC, Q4[2], Q4[3]);
            RD3(GB, 1664); WTn(6); ST1(GD, Q5[0], Q5[1]); REN1(Q5[1]);
            RD3(GC, 1792); WTn(6); ST1(GA, Q5[2], Q5[3]);
            RD3(GD, 1920); WTn(6); ST1(GB, Q6[0], Q6[1]); REN1(Q6[1]);
            WTn(3); ST1(GC, Q6[2], Q6[3]);
            WTn(0); ST1(GD, Q7[0], Q7[1]); REN1(Q7[1]);
            epA = Q7[2]; epZ = Q7[3];                     // carry entry 15
            ro = (ro + 2048u) & 8191u;
            va[0] = lb_base + ro + (uint32_t)(loff0 * 4);
            va[1] = lb_base + ro + (uint32_t)(loff1 * 4);
            va[2] = lb_base + ro;
            cbv = (cbv == bnd_base + 256u) ? bnd_base : cbv + 128u;
            BARR();
        }
        // free-run: chunk F (R steps); all data written before final barrier
        if (R > 0) {
            RD3(GA, 0);
            RD3(GB, 128);
            RDQ(Q0, 0);  RDQ(Q1, 16); RDQ(Q2, 32); RDQ(Q3, 48);
            RDQ(Q4, 64); RDQ(Q5, 80); RDQ(Q6, 96); RDQ(Q7, 112);
            WTn(0);
            RD3(GC, 256); WTn(6); ST1(GA, epA, epZ);
        }
        if (R > 1)  { RD3(GD, 384);  WTn(6); ST1(GB, Q0[0], Q0[1]); REN1(Q0[1]); }
        if (R > 2)  { RD3(GA, 512);  WTn(6); ST1(GC, Q0[2], Q0[3]); }
        if (R > 3)  { RD3(GB, 640);  WTn(6); ST1(GD, Q1[0], Q1[1]); REN1(Q1[1]); }
        if (R > 4)  { RD3(GC, 768);  WTn(6); ST1(GA, Q1[2], Q1[3]); }
        if (R > 5)  { RD3(GD, 896);  WTn(6); ST1(GB, Q2[0], Q2[1]); REN1(Q2[1]); }
        if (R > 6)  { RD3(GA, 1024); WTn(6); ST1(GC, Q2[2], Q2[3]); }
        if (R > 7)  { RD3(GB, 1152); WTn(6); ST1(GD, Q3[0], Q3[1]); REN1(Q3[1]); }
        if (R > 8)  { RD3(GC, 1280); WTn(6); ST1(GA, Q3[2], Q3[3]); }
        if (R > 9)  { RD3(GD, 1408); WTn(6); ST1(GB, Q4[0], Q4[1]); REN1(Q4[1]); }
        if (R > 10) { RD3(GA, 1536); WTn(6); ST1(GC, Q4[2], Q4[3]); }
        if (R > 11) { RD3(GB, 1664); WTn(6); ST1(GD, Q5[0], Q5[1]); REN1(Q5[1]); }
        if (R > 12) { RD3(GC, 1792); WTn(6); ST1(GA, Q5[2], Q5[3]); }
        if (R > 13) { RD3(GD, 1920); WTn(6); ST1(GB, Q6[0], Q6[1]); REN1(Q6[1]); }
        if (R > 14) { WTn(0); ST1(GC, Q6[2], Q6[3]); }
        WTn(0);

        // absolute log-alpha for states 256..511; final states are >= 299
        const float zln2 = (float)z2 * 0.69314718055994530942f;
        sal[256 + 4 * lane + 0] = __logf(a[0]) + zln2;
        sal[256 + 4 * lane + 1] = __logf(a[1]) + zln2;
        sal[256 + 4 * lane + 2] = __logf(a[2]) + zln2;
        sal[256 + 4 * lane + 3] = __logf(a[3]) + zln2;
        asm volatile("s_waitcnt lgkmcnt(0)" ::: "memory");
        SB();
        if (lane == 0) {
            const float x0 = sal[2 * tl - 1];
            const float x1 = sal[2 * tl];
            const float m  = fmaxf(x0, x1);
            float nll = -(m + __logf(__expf(x0 - m) + __expf(x1 - m)));
            if (!(nll < 1e29f)) nll = 0.f;       // zero_infinity (inf/NaN too)
            out_nll[b] = nll / (float)tl;
        }
    }
}

// ---------------------------------------------------------------------------
// Kernel 3: deterministic mean over B
// ---------------------------------------------------------------------------
__global__ void finalize_kernel(const float* __restrict__ nll, float* __restrict__ out)
{
    if (threadIdx.x == 0 && blockIdx.x == 0) {
        float s = 0.f;
        for (int i = 0; i < B_DIM; ++i) s += nll[i];
        out[0] = s * (1.0f / (float)B_DIM);
    }
}

extern "C" void kernel_launch(void* const* d_in, const int* in_sizes, int n_in,
                              void* d_out, int out_size, void* d_ws, size_t ws_size,
                              hipStream_t stream)
{
    const float* pred     = (const float*)d_in[0];
    const int*   targets  = (const int*)d_in[1];
    const int*   in_lens  = (const int*)d_in[2];
    const int*   tgt_lens = (const int*)d_in[3];
    const float* W        = (const float*)d_in[4];
    const float* bias     = (const float*)d_in[5];

    float* probs = (float*)d_ws;                                  // 32*1000*32 f32 = 4.1 MB
    float* nll   = probs + (size_t)B_DIM * T_DIM * VSTRIDE;       // 32 f32
    float* out   = (float*)d_out;

    head_softmax_kernel<<<(B_DIM * T_DIM) / 64, 256, 0, stream>>>(pred, W, bias, probs);
    ctc_alpha_kernel<<<B_DIM, 128, 0, stream>>>(probs, targets, in_lens, tgt_lens, nll);
    finalize_kernel<<<1, 64, 0, stream>>>(nll, out);
}